// Round 2
// baseline (319.228 us; speedup 1.0000x reference)
//
#include <hip/hip_runtime.h>
#include <math.h>

// B=4, S=1024, D=768, H=12, E=64, 3D=2304
// Workspace layout (bytes), total ~137 MB:
//   scbuf fp16 final probs P2 [b][q][g][k] head-minor : 100,663,296 @ 0
//   qkf  fp16 [4096][1536] (Q,K)  : 12,582,912 @ 100,663,296
//   vbuf fp16 [4096][768]  (V)    :  6,291,456 @ 113,246,208
//   ctx  fp16 [4096][768]         :  6,291,456 @ 119,537,664   (reused as dpart before k_pv)
//   x_h  fp16 :  6,291,456 @ 125,829,120                       (reused as dfinal after k_qkv)
//   wq_h fp16 :  3,538,944 @ 132,120,576
//   wp_h fp16 :  1,179,648 @ 135,659,520
//
// New structure: scores never round-trip HBM. All-heads QK tile (64q x 32k,
// 12 heads in MFMA accs) is computed twice: passA emits softmax partial sums,
// passB recomputes, normalizes with 1/d, applies mix2, stores P2 directly.

typedef _Float16 f16;
typedef __attribute__((ext_vector_type(8))) _Float16 f16x8;
typedef __attribute__((ext_vector_type(2))) _Float16 f16x2;
typedef __attribute__((ext_vector_type(4))) float f32x4;
typedef __attribute__((ext_vector_type(2))) float f32x2;
typedef unsigned short u16;

__device__ __forceinline__ u16 f2h(float f) {      // RTN convert
  f16 h = (f16)f;
  return __builtin_bit_cast(u16, h);
}
__device__ __forceinline__ unsigned pk2h(float a, float b) {
  return __builtin_bit_cast(unsigned, __builtin_amdgcn_cvt_pkrtz(a, b));
}

__device__ __forceinline__ void async16(const void* g, void* l) {
  __builtin_amdgcn_global_load_lds(
      (const __attribute__((address_space(1))) unsigned int*)g,
      (__attribute__((address_space(3))) unsigned int*)l, 16, 0, 0);
}

#define MFMA_F16(a, b, c) __builtin_amdgcn_mfma_f32_16x16x32_f16((a), (b), (c), 0, 0, 0)

// ---------------- prep: cast x, Wqkv, Wp to fp16 ----------------
__global__ __launch_bounds__(256) void k_prep(const float* __restrict__ x,
                                              const float* __restrict__ Wqkv,
                                              const float* __restrict__ Wp,
                                              u16* __restrict__ xh,
                                              u16* __restrict__ wh,
                                              u16* __restrict__ wph) {
  const int blk = blockIdx.x, t = threadIdx.x;
  if (blk < 3072) {
    int i = blk * 256 + t;
    float4 v = ((const float4*)x)[i];
    ((ushort4*)xh)[i] = make_ushort4(f2h(v.x), f2h(v.y), f2h(v.z), f2h(v.w));
  } else if (blk < 4800) {
    int i = (blk - 3072) * 256 + t;
    float4 v = ((const float4*)Wqkv)[i];
    ((ushort4*)wh)[i] = make_ushort4(f2h(v.x), f2h(v.y), f2h(v.z), f2h(v.w));
  } else {
    int i = (blk - 4800) * 256 + t;
    float4 v = ((const float4*)Wp)[i];
    ((ushort4*)wph)[i] = make_ushort4(f2h(v.x), f2h(v.y), f2h(v.z), f2h(v.w));
  }
}

// ---------------- K1: qkv = x @ Wqkv^T, fp16 single-MFMA ----------------
// M=4096 N=2304 K=768; 1-D grid 576 with GROUP_M=8 swizzle.
// Q,K cols -> qkf[4096][1536]; V cols (n0>=1536) -> vbuf[4096][768].
__global__ __launch_bounds__(256) void k_qkv(const u16* __restrict__ Axh,
                                             const u16* __restrict__ Bwh,
                                             u16* __restrict__ qkf,
                                             u16* __restrict__ vbuf) {
  __shared__ u16 smem[16384];   // 32 KB: [0:4096)=As, [4096:8192)=Bs; whole = repack T
  u16* As = smem;
  u16* Bs = smem + 4096;
  const int t = threadIdx.x, lane = t & 63, wave = t >> 6;
  const int wm = wave >> 1, wn = wave & 1;
  const int quad = lane >> 4, l16 = lane & 15;
  const int pid = blockIdx.x;
  const int group = pid / 144;              // 144 = 8 * 18
  const int rem = pid - group * 144;
  const int m0 = (group * 8 + (rem & 7)) * 128;
  const int n0 = (rem >> 3) * 128;
  const bool vblk = (n0 >= 1536);
  const int srow = t >> 2, sch = (t & 3) * 8;
  f32x4 acc[4][4];
#pragma unroll
  for (int i = 0; i < 4; ++i)
#pragma unroll
    for (int j = 0; j < 4; ++j) acc[i][j] = (f32x4){0.f, 0.f, 0.f, 0.f};
  for (int k0 = 0; k0 < 768; k0 += 32) {
    const size_t ga = (size_t)(m0 + srow) * 768 + k0 + sch;
    const size_t gb = (size_t)(n0 + srow) * 768 + k0 + sch;
    __syncthreads();
    async16(Axh + ga, &As[t * 8]);
    async16(Axh + ga + (size_t)64 * 768, &As[2048 + t * 8]);
    async16(Bwh + gb, &Bs[t * 8]);
    async16(Bwh + gb + (size_t)64 * 768, &Bs[2048 + t * 8]);
    __syncthreads();
    f16x8 af[4], bfr[4];
#pragma unroll
    for (int i = 0; i < 4; ++i) af[i] = *(const f16x8*)&As[(wm * 64 + i * 16 + l16) * 32 + quad * 8];
#pragma unroll
    for (int j = 0; j < 4; ++j) bfr[j] = *(const f16x8*)&Bs[(wn * 64 + j * 16 + l16) * 32 + quad * 8];
#pragma unroll
    for (int i = 0; i < 4; ++i)
#pragma unroll
      for (int j = 0; j < 4; ++j) acc[i][j] = MFMA_F16(af[i], bfr[j], acc[i][j]);
  }
  __syncthreads();
  u16* T = smem;
#pragma unroll
  for (int i = 0; i < 4; ++i)
#pragma unroll
    for (int j = 0; j < 4; ++j)
#pragma unroll
      for (int r = 0; r < 4; ++r) {
        const int row = wm * 64 + i * 16 + quad * 4 + r;
        const int col = wn * 64 + j * 16 + l16;
        T[row * 128 + (col ^ ((row & 7) << 4))] = f2h(acc[i][j][r]);
      }
  __syncthreads();
  const int row = t >> 1, halfc = (t & 1) * 64;
  const int sw = (row & 7) << 4;
  u16* dst = vblk ? (vbuf + (size_t)(m0 + row) * 768 + (n0 - 1536) + halfc)
                  : (qkf + (size_t)(m0 + row) * 1536 + n0 + halfc);
#pragma unroll
  for (int c = 0; c < 64; c += 8)
    *(uint4*)(dst + c) = *(const uint4*)&T[row * 128 + ((halfc + c) ^ sw)];
}

// ---------------- shared body: all-heads QK tile (64q x 32k, 12 heads) ----------------
// acc[h][j] : C rows = wave*16 + quad*4 + r, cols = j*16 + l16 (k-keys)
__device__ __forceinline__ void qk_heads(const u16* __restrict__ qkf,
                                         int b, int q0, int k0, int t,
                                         u16* As, u16* Bs,
                                         f32x4 (&acc)[12][2]) {
  const int lane = t & 63, wave = t >> 6;
  const int quad = lane >> 4, l16 = lane & 15;
  (void)quad;
#pragma unroll
  for (int h = 0; h < 12; ++h)
#pragma unroll
    for (int j = 0; j < 2; ++j) acc[h][j] = (f32x4){0.f, 0.f, 0.f, 0.f};
  const int srow = t >> 2, sch = (t & 3) * 8;
#pragma unroll
  for (int h = 0; h < 12; ++h) {
    __syncthreads();
    {
      const size_t ga = (size_t)(b * 1024 + q0 + srow) * 1536 + h * 64 + sch;
      async16(qkf + ga, &As[t * 8]);               // chunk 0: feats h*64..+31
      async16(qkf + ga + 32, &As[2048 + t * 8]);   // chunk 1: feats h*64+32..+63
    }
    if (t < 128) {
      const size_t gb = (size_t)(b * 1024 + k0 + srow) * 1536 + 768 + h * 64 + sch;
      async16(qkf + gb, &Bs[t * 8]);
      async16(qkf + gb + 32, &Bs[1024 + t * 8]);
    }
    __syncthreads();
#pragma unroll
    for (int c = 0; c < 2; ++c) {
      f16x8 af = *(const f16x8*)&As[c * 2048 + (wave * 16 + l16) * 32 + (lane >> 4) * 8];
      f16x8 bf0 = *(const f16x8*)&Bs[c * 1024 + (l16) * 32 + (lane >> 4) * 8];
      f16x8 bf1 = *(const f16x8*)&Bs[c * 1024 + (16 + l16) * 32 + (lane >> 4) * 8];
      acc[h][0] = MFMA_F16(af, bf0, acc[h][0]);
      acc[h][1] = MFMA_F16(af, bf1, acc[h][1]);
    }
  }
}

__device__ __forceinline__ void mix1_g(const f32x4 (&acc)[12][2], const float* wl_s,
                                       float b0, int g, f32x4& L0, f32x4& L1) {
  L0 = (f32x4){b0, b0, b0, b0};
  L1 = L0;
#pragma unroll
  for (int h = 0; h < 12; ++h) {
    const float w = wl_s[g * 12 + h];
    const f32x4 wv = {w, w, w, w};
    L0 = __builtin_elementwise_fma(wv, acc[h][0], L0);
    L1 = __builtin_elementwise_fma(wv, acc[h][1], L1);
  }
}

// ---------------- passA: QK + mix1 + exp -> partial row sums ----------------
// grid (kt=32, qt=16, b=4). dpart[b*16+qt][kt][row*12+g] f32.
__global__ __launch_bounds__(256) void k_qkmix_sum(const u16* __restrict__ qkf,
                                                   const float* __restrict__ Wl,
                                                   const float* __restrict__ bl,
                                                   float* __restrict__ dpart) {
  __shared__ u16 As[4096];
  __shared__ u16 Bs[2048];
  __shared__ float wl_s[144], bl_s[12];
  __shared__ float dred[768];
  const int t = threadIdx.x;
  if (t < 144) wl_s[t] = Wl[t];
  if (t < 12) bl_s[t] = bl[t];
  const int kt = blockIdx.x, qt = blockIdx.y, b = blockIdx.z;
  const int q0 = qt * 64, k0 = kt * 32;
  f32x4 acc[12][2];
  qk_heads(qkf, b, q0, k0, t, As, Bs, acc);
  const int lane = t & 63, wave = t >> 6;
  const int quad = lane >> 4, l16 = lane & 15;
  f32x4 rs[12];
#pragma unroll
  for (int g = 0; g < 12; ++g) {
    f32x4 L0, L1;
    mix1_g(acc, wl_s, bl_s[g] - 16.f, g, L0, L1);
    f32x4 e0, e1;
#pragma unroll
    for (int r = 0; r < 4; ++r) { e0[r] = __expf(L0[r]); e1[r] = __expf(L1[r]); }
    rs[g] = e0 + e1;
  }
  // butterfly over l16 lanes (cols)
#pragma unroll
  for (int m = 1; m <= 8; m <<= 1) {
#pragma unroll
    for (int g = 0; g < 12; ++g) {
      f32x4 o;
#pragma unroll
      for (int r = 0; r < 4; ++r) o[r] = __shfl_xor(rs[g][r], m);
      rs[g] += o;
    }
  }
  if (l16 == 0) {
#pragma unroll
    for (int g = 0; g < 12; ++g)
#pragma unroll
      for (int r = 0; r < 4; ++r)
        dred[(wave * 16 + quad * 4 + r) * 12 + g] = rs[g][r];
  }
  __syncthreads();
  const size_t base = (size_t)((b * 16 + qt) * 32 + kt) * 768;
  for (int s = t; s < 768; s += 256) dpart[base + s] = dred[s];
}

// ---------------- k_dsum: reduce partials over kt, invert ----------------
// grid 192 (= 64 bq * 3). dfinal[bq*768 + row*12 + g] = 1/sum.
__global__ __launch_bounds__(256) void k_dsum(const float* __restrict__ dpart,
                                              float* __restrict__ dfinal) {
  const int blk = blockIdx.x;
  const int bq = blk / 3, part = blk % 3;
  const int slot = part * 256 + threadIdx.x;
  const float* p = dpart + (size_t)bq * 24576 + slot;
  float s = 0.f;
#pragma unroll
  for (int kt = 0; kt < 32; ++kt) s += p[kt * 768];
  dfinal[(size_t)bq * 768 + slot] = 1.0f / s;
}

// ---------------- passB: QK + mix1 + exp*dinv + mix2 -> store P2 ----------------
// grid (kt=32, qt=16, b=4). Output scbuf [b][q][g][k] head-minor (unchanged layout).
__global__ __launch_bounds__(256) void k_qkmix_store(const u16* __restrict__ qkf,
                                                     const float* __restrict__ Wl,
                                                     const float* __restrict__ bl,
                                                     const float* __restrict__ Ww,
                                                     const float* __restrict__ bw,
                                                     const float* __restrict__ dfinal,
                                                     u16* __restrict__ scbuf) {
  __shared__ u16 As[4096];
  __shared__ u16 Bs[2048];
  __shared__ u16 Tout[64 * 40];   // repack tile, stride 40 u16 (16B-aligned, <=2-way banks)
  __shared__ float wl_s[144], ww_s[144], bl_s[12], bw_s[12];
  __shared__ float dinv_s[768];
  const int t = threadIdx.x;
  if (t < 144) { wl_s[t] = Wl[t]; ww_s[t] = Ww[t]; }
  if (t < 12)  { bl_s[t] = bl[t]; bw_s[t] = bw[t]; }
  const int kt = blockIdx.x, qt = blockIdx.y, b = blockIdx.z;
  const int q0 = qt * 64, k0 = kt * 32;
  {
    const size_t dbase = (size_t)(b * 16 + qt) * 768;
    for (int s = t; s < 768; s += 256) dinv_s[s] = dfinal[dbase + s];
  }
  f32x4 acc[12][2];
  qk_heads(qkf, b, q0, k0, t, As, Bs, acc);   // internal barriers make smem inits visible
  const int lane = t & 63, wave = t >> 6;
  const int quad = lane >> 4, l16 = lane & 15;
  f32x4 P[12][2];
#pragma unroll
  for (int g = 0; g < 12; ++g) {
    f32x4 L0, L1;
    mix1_g(acc, wl_s, bl_s[g] - 16.f, g, L0, L1);
    f32x4 dv;
#pragma unroll
    for (int r = 0; r < 4; ++r) dv[r] = dinv_s[(wave * 16 + quad * 4 + r) * 12 + g];
#pragma unroll
    for (int r = 0; r < 4; ++r) {
      P[g][0][r] = __expf(L0[r]) * dv[r];
      P[g][1][r] = __expf(L1[r]) * dv[r];
    }
  }
  const int orow = t >> 2, oc = (t & 3) * 8;
  const size_t obase0 = (size_t)(b * 1024 + q0 + orow) * 12;
#pragma unroll
  for (int g2 = 0; g2 < 12; ++g2) {
    f32x4 O0 = (f32x4){bw_s[g2], bw_s[g2], bw_s[g2], bw_s[g2]}, O1 = O0;
#pragma unroll
    for (int h = 0; h < 12; ++h) {
      const float w = ww_s[g2 * 12 + h];
      const f32x4 wv = {w, w, w, w};
      O0 = __builtin_elementwise_fma(wv, P[h][0], O0);
      O1 = __builtin_elementwise_fma(wv, P[h][1], O1);
    }
    __syncthreads();   // protect Tout from previous iteration's readers
#pragma unroll
    for (int r = 0; r < 4; ++r) {
      const int row = wave * 16 + quad * 4 + r;
      Tout[row * 40 + l16] = f2h(O0[r]);
      Tout[row * 40 + 16 + l16] = f2h(O1[r]);
    }
    __syncthreads();
    uint4 v = *(const uint4*)&Tout[orow * 40 + oc];
    *(uint4*)(scbuf + (obase0 + g2) * 1024 + k0 + oc) = v;
  }
}

// ---------------- K4: ctx = P2(fp16) @ V(fp16) per (b,h); V transposed in-LDS ----------------
// M=1024 N=64 K=1024; BM=128; waves 2x2, each 64x32 (4x2 frags). P head-minor.
__global__ __launch_bounds__(256) void k_pv(const u16* __restrict__ probs,
                                            const u16* __restrict__ vbuf,
                                            u16* __restrict__ ctx) {
  __shared__ u16 As[4096];      // 128x32 P tile
  __shared__ u16 Bs[64 * 40];   // V^T tile: [e][s-chunk 32], row stride 40 (16B-aligned)
  const int t = threadIdx.x, lane = t & 63, wave = t >> 6;
  const int wm = wave >> 1, wn = wave & 1;
  const int quad = lane >> 4, l16 = lane & 15;
  const int bh = blockIdx.y, b = bh / 12, h = bh % 12;
  const int m0 = blockIdx.x * 128;
  const int srow = t >> 2, sch = (t & 3) * 8;
  const int ev = t & 63, s8 = (t >> 6) * 8;   // V transpose-load: e=ev, s-chunk s8
  f32x4 acc[4][2];
#pragma unroll
  for (int i = 0; i < 4; ++i)
#pragma unroll
    for (int j = 0; j < 2; ++j) acc[i][j] = (f32x4){0.f, 0.f, 0.f, 0.f};
  for (int k0 = 0; k0 < 1024; k0 += 32) {
    const u16* vp = vbuf + (size_t)(b * 1024 + k0 + s8) * 768 + h * 64 + ev;
    u16 vcol[8];
#pragma unroll
    for (int i = 0; i < 8; ++i) vcol[i] = vp[(size_t)i * 768];
    __syncthreads();
    const u16* ga = probs + ((size_t)(b * 1024 + m0 + srow) * 12 + h) * 1024 + k0 + sch;
    async16(ga, &As[t * 8]);
    async16(ga + (size_t)64 * 12 * 1024, &As[2048 + t * 8]);
    *(ushort4*)&Bs[ev * 40 + s8] = make_ushort4(vcol[0], vcol[1], vcol[2], vcol[3]);
    *(ushort4*)&Bs[ev * 40 + s8 + 4] = make_ushort4(vcol[4], vcol[5], vcol[6], vcol[7]);
    __syncthreads();
    f16x8 af[4], bfr[2];
#pragma unroll
    for (int i = 0; i < 4; ++i) af[i] = *(const f16x8*)&As[(wm * 64 + i * 16 + l16) * 32 + quad * 8];
#pragma unroll
    for (int j = 0; j < 2; ++j) bfr[j] = *(const f16x8*)&Bs[(wn * 32 + j * 16 + l16) * 40 + quad * 8];
#pragma unroll
    for (int i = 0; i < 4; ++i)
#pragma unroll
      for (int j = 0; j < 2; ++j) acc[i][j] = MFMA_F16(af[i], bfr[j], acc[i][j]);
  }
#pragma unroll
  for (int i = 0; i < 4; ++i)
#pragma unroll
    for (int j = 0; j < 2; ++j)
#pragma unroll
      for (int r = 0; r < 4; ++r) {
        int q = m0 + wm * 64 + i * 16 + quad * 4 + r;
        int e = wn * 32 + j * 16 + l16;
        ctx[(size_t)(b * 1024 + q) * 768 + h * 64 + e] = f2h(acc[i][j][r]);
      }
}

// ---------------- K5: out = ctx @ Wp^T + bp (fp16 MFMA, fp32 out) ----------------
// M=4096 N=768 K=768
__global__ __launch_bounds__(256) void k_oproj(const u16* __restrict__ A,
                                               const u16* __restrict__ Bm,
                                               const float* __restrict__ bp,
                                               float* __restrict__ out) {
  __shared__ u16 As[4096];
  __shared__ u16 Bs[4096];
  const int t = threadIdx.x, lane = t & 63, wave = t >> 6;
  const int wm = wave >> 1, wn = wave & 1;
  const int quad = lane >> 4, l16 = lane & 15;
  const int m0 = blockIdx.y * 128, n0 = blockIdx.x * 128;
  const int srow = t >> 2, sch = (t & 3) * 8;
  f32x4 acc[4][4];
#pragma unroll
  for (int i = 0; i < 4; ++i)
#pragma unroll
    for (int j = 0; j < 4; ++j) acc[i][j] = (f32x4){0.f, 0.f, 0.f, 0.f};
  for (int k0 = 0; k0 < 768; k0 += 32) {
    __syncthreads();
    const u16* ga = A + (size_t)(m0 + srow) * 768 + k0 + sch;
    const u16* gb = Bm + (size_t)(n0 + srow) * 768 + k0 + sch;
    async16(ga, &As[t * 8]);
    async16(ga + (size_t)64 * 768, &As[2048 + t * 8]);
    async16(gb, &Bs[t * 8]);
    async16(gb + (size_t)64 * 768, &Bs[2048 + t * 8]);
    __syncthreads();
    f16x8 af[4], bfr[4];
#pragma unroll
    for (int i = 0; i < 4; ++i) af[i] = *(const f16x8*)&As[(wm * 64 + i * 16 + l16) * 32 + quad * 8];
#pragma unroll
    for (int j = 0; j < 4; ++j) bfr[j] = *(const f16x8*)&Bs[(wn * 64 + j * 16 + l16) * 32 + quad * 8];
#pragma unroll
    for (int i = 0; i < 4; ++i)
#pragma unroll
      for (int j = 0; j < 4; ++j) acc[i][j] = MFMA_F16(af[i], bfr[j], acc[i][j]);
  }
#pragma unroll
  for (int i = 0; i < 4; ++i)
#pragma unroll
    for (int j = 0; j < 4; ++j)
#pragma unroll
      for (int r = 0; r < 4; ++r) {
        const int row = m0 + wm * 64 + i * 16 + quad * 4 + r;
        const int col = n0 + wn * 64 + j * 16 + l16;
        out[(size_t)row * 768 + col] = acc[i][j][r] + bp[col];
      }
}

extern "C" void kernel_launch(void* const* d_in, const int* in_sizes, int n_in,
                              void* d_out, int out_size, void* d_ws, size_t ws_size,
                              hipStream_t stream) {
  const float* x    = (const float*)d_in[0];
  const float* Wqkv = (const float*)d_in[1];
  const float* Wl   = (const float*)d_in[2];
  const float* bl   = (const float*)d_in[3];
  const float* Ww   = (const float*)d_in[4];
  const float* bw   = (const float*)d_in[5];
  const float* Wp   = (const float*)d_in[6];
  const float* bp   = (const float*)d_in[7];
  float* out = (float*)d_out;

  char* ws = (char*)d_ws;
  u16* scbuf   = (u16*)(ws + 0);               // 100,663,296 B, P2 [b][q][g][k]
  u16* qkf     = (u16*)(ws + 100663296ull);    //  12,582,912 B
  u16* vbuf    = (u16*)(ws + 113246208ull);    //   6,291,456 B
  u16* ctx     = (u16*)(ws + 119537664ull);    //   6,291,456 B
  float* dpart = (float*)(ws + 119537664ull);  //   6,291,456 B (dead before k_pv writes ctx)
  u16* x_h     = (u16*)(ws + 125829120ull);    //   6,291,456 B
  float* dfinal= (float*)(ws + 125829120ull);  //     196,608 B (x_h dead after k_qkv)
  u16* wq_h    = (u16*)(ws + 132120576ull);    //   3,538,944 B
  u16* wp_h    = (u16*)(ws + 135659520ull);    //   1,179,648 B

  hipLaunchKernelGGL(k_prep, dim3(5376), dim3(256), 0, stream,
                     x, Wqkv, Wp, x_h, wq_h, wp_h);
  hipLaunchKernelGGL(k_qkv, dim3(576), dim3(256), 0, stream, x_h, wq_h, qkf, vbuf);
  hipLaunchKernelGGL(k_qkmix_sum, dim3(32, 16, 4), dim3(256), 0, stream, qkf, Wl, bl, dpart);
  hipLaunchKernelGGL(k_dsum, dim3(192), dim3(256), 0, stream, dpart, dfinal);
  hipLaunchKernelGGL(k_qkmix_store, dim3(32, 16, 4), dim3(256), 0, stream,
                     qkf, Wl, bl, Ww, bw, dfinal, scbuf);
  hipLaunchKernelGGL(k_pv, dim3(8, 48), dim3(256), 0, stream, scbuf, vbuf, ctx);
  hipLaunchKernelGGL(k_oproj, dim3(6, 32), dim3(256), 0, stream, ctx, wp_h, bp, out);
}